// Round 16
// baseline (185.349 us; speedup 1.0000x reference)
//
#include <hip/hip_runtime.h>

#define N_NODES 20000
#define DEG 16
#define GRAPHS 16
#define NPG 1250

typedef __bf16 bf16x8 __attribute__((ext_vector_type(8)));
typedef float f32x4 __attribute__((ext_vector_type(4)));
#define MFMA16(a, b, c) __builtin_amdgcn_mfma_f32_16x16x32_bf16(a, b, c, 0, 0, 0)

// LDS-only barrier: waits LDS ops, does NOT drain vmcnt.
__device__ __forceinline__ void ldsbar() {
    __asm__ volatile("s_waitcnt lgkmcnt(0)\n\ts_barrier" ::: "memory");
}
// async global->LDS direct copy, 16 B per lane; LDS dest = uniform base + lane*16
__device__ __forceinline__ void async16(void* lds, const void* g) {
    __builtin_amdgcn_global_load_lds(
        (const __attribute__((address_space(1))) unsigned int*)(g),
        (__attribute__((address_space(3))) unsigned int*)(lds), 16, 0, 0);
}

// ---- workspace layout ----
#define OFF_X1    0            // x1 [20000][128] bf16
#define OFF_P1    2560000      // c1W1 packed: MT=8  KT=1 -> 4096
#define OFF_P2    2564096      // c1W2 packed: MT=8  KT=4 -> 16384
#define OFF_P3    2580480      // c2W1 packed: MT=16 KT=5 -> 40960
#define OFF_P4    2621440      // c2W2 packed: MT=16 KT=8 -> 65536
#define OFF_POOL_BYTES 5373952 // pooled u32[16*256]
#define OFF_MSGE  2695176      // msgE (bf16 elems): row e = [sx,sy,sz,rx,ry,rz,0,0]
#define ZROW      320000       //   row 320000 = zeros

// =================== prep: pack weights + pooled init + edge messages =========
__global__ __launch_bounds__(256) void prep_kernel(
    const float* __restrict__ pos, const int* __restrict__ esrc,
    const float* __restrict__ c1W1, const float* __restrict__ c1W2,
    const float* __restrict__ c2W1, const float* __restrict__ c2W2,
    __bf16* __restrict__ p1, __bf16* __restrict__ p2,
    __bf16* __restrict__ p3, __bf16* __restrict__ p4,
    unsigned int* __restrict__ pooled, __bf16* __restrict__ msgE)
{
    int t = blockIdx.x * 256 + threadIdx.x;
    {   // gatherE: one edge per thread
        int e = t, d = e >> 4;
        int s = esrc[e];
        float sx = pos[3*s], sy = pos[3*s+1], sz = pos[3*s+2];
        float dx = pos[3*d], dy = pos[3*d+1], dz = pos[3*d+2];
        bf16x8 v;
        v[0] = (__bf16)sx; v[1] = (__bf16)sy; v[2] = (__bf16)sz;
        v[3] = (__bf16)(sx - dx); v[4] = (__bf16)(sy - dy); v[5] = (__bf16)(sz - dz);
        v[6] = (__bf16)0.f; v[7] = (__bf16)0.f;
        *(bf16x8*)&msgE[(size_t)e * 8] = v;
    }
    if (t < GRAPHS * 256) pooled[t] = 0u;             // flipped(-inf) == 0
    if (t == 0) {
        bf16x8 z;
        #pragma unroll
        for (int j = 0; j < 8; j++) z[j] = (__bf16)0.f;
        *(bf16x8*)&msgE[(size_t)ZROW * 8] = z;
    }
    if (t >= 15872) return;
    const float* W; __bf16* out; int M, Kreal, KT, grp; bool c2w1 = false;
    if      (t <  512)  { W = c1W1; out = p1; M = 128; Kreal =   6; KT = 1; grp = t; }
    else if (t < 2560)  { W = c1W2; out = p2; M = 128; Kreal = 128; KT = 4; grp = t - 512; }
    else if (t < 7680)  { W = c2W1; out = p3; M = 256; Kreal = 131; KT = 5; grp = t - 2560; c2w1 = true; }
    else                { W = c2W2; out = p4; M = 256; Kreal = 256; KT = 8; grp = t - 7680; }
    int lane = grp & 63, rest = grp >> 6;
    int kt = rest % KT, mt = rest / KT;
    int m = mt * 16 + (lane & 15);
    int kbase = kt * 32 + ((lane >> 4) << 3);
    bf16x8 v;
    #pragma unroll
    for (int j = 0; j < 8; j++) {
        int ks = kbase + j;
        int wr;
        if (c2w1) wr = (ks < 128) ? ks : ((ks >= 131 && ks < 134) ? ks - 3 : -1);
        else      wr = (ks < Kreal) ? ks : -1;
        v[j] = (wr >= 0) ? (__bf16)W[wr * M + m] : (__bf16)0.f;
    }
    *(bf16x8*)&out[grp * 8] = v;
}

// =================== conv1 v3 =================== (R15, unchanged)
#define NB1T 16
#define NT1 5
__global__ __launch_bounds__(512, 2) void conv1_kernel(
    const __bf16* __restrict__ msgE,
    const __bf16* __restrict__ W1p, const float* __restrict__ b1,
    const __bf16* __restrict__ W2p, const float* __restrict__ b2,
    __bf16* __restrict__ x1)
{
    __shared__ __attribute__((aligned(16))) __bf16 msgF[3][NB1T * 64 * 8];   // 3x16 KB
    __shared__ __attribute__((aligned(16))) __bf16 hidF[NB1T * 4 * 64 * 8];  // 64 KB
    const int tid = threadIdx.x, lane = tid & 63, wave = tid >> 6;
    const int quad = lane >> 4, col = lane & 15;
    const int base = blockIdx.x * (NB1T * NT1);

    bf16x8 A1 = *(const bf16x8*)&W1p[(wave * 64 + lane) * 8];
    f32x4 bias1 = *(const f32x4*)&b1[wave * 16 + quad * 4];
    bf16x8 B2w[4];
    #pragma unroll
    for (int kt = 0; kt < 4; kt++)
        B2w[kt] = *(const bf16x8*)&W2p[((wave * 4 + kt) * 64 + lane) * 8];
    float b2v = b2[wave * 16 + col];

    auto stage = [&](int td, int buf) {
        #pragma unroll
        for (int s = 0; s < 2; s++) {
            int nl = wave * 2 + s;
            int row = (quad == 0) ? ((base + td * NB1T + nl) * 16 + col) : ZROW;
            async16(&msgF[buf][nl * 64 * 8], &msgE[(size_t)row * 8]);
        }
    };
    stage(0, 0);
    stage(1, 1);

    for (int k = 0; k < NT1; k++) {
        int td = k + 2; if (td >= NT1) td -= NT1;
        stage(td, (k + 2) % 3);
        __asm__ volatile("s_waitcnt vmcnt(4)" ::: "memory");
        const int bufi = k % 3;
        #pragma unroll
        for (int nl = 0; nl < NB1T; nl++) {
            bf16x8 B = *(const bf16x8*)&msgF[bufi][(nl * 64 + lane) * 8];
            f32x4 acc = bias1;
            acc = MFMA16(A1, B, acc);
            union { __bf16 h[4]; uint2 u; } pk;
            #pragma unroll
            for (int r = 0; r < 4; r++) pk.h[r] = (__bf16)fmaxf(acc[r], 0.f);
            int kt2 = wave >> 1;
            int lane2 = ((wave * 2 + (quad >> 1)) & 3) * 16 + col;
            int j0 = (quad & 1) * 4;
            *(uint2*)&hidF[((nl * 4 + kt2) * 64 + lane2) * 8 + j0] = pk.u;
        }
        ldsbar();
        const int n0 = base + k * NB1T;
        #pragma unroll
        for (int nl = 0; nl < NB1T; nl++) {
            bf16x8 hA[4];
            #pragma unroll
            for (int kt = 0; kt < 4; kt++)
                hA[kt] = *(const bf16x8*)&hidF[((nl * 4 + kt) * 64 + lane) * 8];
            f32x4 acc = {0.f, 0.f, 0.f, 0.f};
            #pragma unroll
            for (int kt = 0; kt < 4; kt++) acc = MFMA16(hA[kt], B2w[kt], acc);
            float m = fmaxf(fmaxf(acc[0], acc[1]), fmaxf(acc[2], acc[3]));
            m = fmaxf(m, __shfl_xor(m, 16));
            m = fmaxf(m, __shfl_xor(m, 32));
            if (lane < 16)
                x1[(size_t)(n0 + nl) * 128 + wave * 16 + lane] = (__bf16)(m + b2v);
        }
        ldsbar();
    }
}

// =================== conv2: 768 threads, 3 waves/SIMD ===================
// 250 blocks x 768 thr x 80 nodes (NT2=20 tiles of NB2=4). 4 producer waves
// (4 mtiles each, A1[4][5]=80 regs) + 8 consumer waves (2 ch-tiles each,
// B2r[2][8]=64 regs). waves_per_eu(3,3) -> ~170-reg budget/wave, no spill,
// 3 waves/SIMD (1P+2C per SIMD) = 50% more latency hiding than R15's 2.
#define NB2 4
#define NT2 20
__global__ __launch_bounds__(768) __attribute__((amdgpu_waves_per_eu(3, 3)))
void conv2_kernel(
    const int* __restrict__ esrc,
    const __bf16* __restrict__ x1, const __bf16* __restrict__ msgE,
    const __bf16* __restrict__ W1p, const float* __restrict__ b1,
    const __bf16* __restrict__ W2p, const float* __restrict__ b2,
    unsigned int* __restrict__ pooled)
{
    __shared__ __attribute__((aligned(16))) __bf16 msgF[3][NB2 * 5 * 64 * 8];  // 3x20 KB
    __shared__ __attribute__((aligned(16))) __bf16 hidF[2][NB2 * 8 * 64 * 8];  // 2x32 KB
    __shared__ int sSrc[NB2 * NT2 * 16];                                       // 5.1 KB
    const int tid = threadIdx.x, lane = tid & 63, wave = tid >> 6;
    const int quad = lane >> 4, col = lane & 15;
    const int base = blockIdx.x * (NB2 * NT2);

    for (int u = tid; u < NB2 * NT2 * 16; u += 768) sSrc[u] = esrc[base * 16 + u];
    __syncthreads();

    if (wave < 4) {
        // ===== producer: layer 1, 4 mtiles/wave =====
        bf16x8 A1[4][5];
        f32x4 bias1[4];
        #pragma unroll
        for (int i = 0; i < 4; i++) {
            int tg = wave * 4 + i;
            #pragma unroll
            for (int kt = 0; kt < 5; kt++)
                A1[i][kt] = *(const bf16x8*)&W1p[((tg * 5 + kt) * 64 + lane) * 8];
            bias1[i] = *(const f32x4*)&b1[tg * 16 + quad * 4];
        }

        auto stage = [&](int td, int buf) {        // 20 groups / 4 waves = 5 each
            #pragma unroll
            for (int s = 0; s < 5; s++) {
                int g = wave + 4 * s;
                int nl = g / 5, kt = g % 5;
                __bf16* ldst = &msgF[buf][g * 64 * 8];
                const __bf16* gsrc;
                if (kt < 4) {
                    int src = sSrc[(td * NB2 + nl) * 16 + col];
                    gsrc = &x1[(size_t)src * 128 + kt * 32 + quad * 8];
                } else {
                    int row = (quad == 0) ? ((base + td * NB2 + nl) * 16 + col) : ZROW;
                    gsrc = &msgE[(size_t)row * 8];
                }
                async16(ldst, gsrc);
            }
        };

        stage(0, 0);
        stage(1, 1);

        for (int k = 0; k < NT2; k++) {
            int td = k + 2;
            if (td >= NT2) td -= NT2;
            stage(td, (k + 2) % 3);
            __asm__ volatile("s_waitcnt vmcnt(10)" ::: "memory");  // tile-k done
            const int bufi = k % 3, bufo = k & 1;
            #pragma unroll
            for (int nl = 0; nl < NB2; nl++) {
                bf16x8 B[5];
                #pragma unroll
                for (int kt = 0; kt < 5; kt++)
                    B[kt] = *(const bf16x8*)&msgF[bufi][((nl * 5 + kt) * 64 + lane) * 8];
                #pragma unroll
                for (int i = 0; i < 4; i++) {
                    int mtg = wave * 4 + i;
                    f32x4 acc = bias1[i];
                    #pragma unroll
                    for (int kt = 0; kt < 5; kt++) acc = MFMA16(A1[i][kt], B[kt], acc);
                    union { __bf16 h[4]; uint2 u; } pk;
                    #pragma unroll
                    for (int r = 0; r < 4; r++) pk.h[r] = (__bf16)fmaxf(acc[r], 0.f);
                    int kt2 = mtg >> 1;
                    int lane2 = ((mtg * 2 + (quad >> 1)) & 3) * 16 + col;
                    int j0 = (quad & 1) * 4;
                    *(uint2*)&hidF[bufo][((nl * 8 + kt2) * 64 + lane2) * 8 + j0] = pk.u;
                }
            }
            ldsbar();
        }
    } else {
        // ===== consumer: layer 2 + fused global max-pool, 2 ch-tiles/wave =====
        const int wv = wave - 4;                   // 0..7
        bf16x8 B2r[2][8];
        #pragma unroll
        for (int i = 0; i < 2; i++) {
            int tg = wv * 2 + i;
            #pragma unroll
            for (int kt = 0; kt < 8; kt++)
                B2r[i][kt] = *(const bf16x8*)&W2p[((tg * 8 + kt) * 64 + lane) * 8];
        }
        f32x4 runmax[2];
        #pragma unroll
        for (int i = 0; i < 2; i++)
            #pragma unroll
            for (int r = 0; r < 4; r++) runmax[i][r] = -3.4e38f;
        int gprev = base / NPG;

        auto flushfn = [&]() {
            #pragma unroll
            for (int i = 0; i < 2; i++) {
                float v = fmaxf(fmaxf(runmax[i][0], runmax[i][1]),
                                fmaxf(runmax[i][2], runmax[i][3]));
                v = fmaxf(v, __shfl_xor(v, 16));
                v = fmaxf(v, __shfl_xor(v, 32));
                if (lane < 16) {
                    int c = (wv * 2 + i) * 16 + lane;
                    float val = v + b2[c];
                    unsigned u = __float_as_uint(val);
                    u = (u & 0x80000000u) ? ~u : (u | 0x80000000u);
                    atomicMax(&pooled[gprev * 256 + c], u);
                }
                #pragma unroll
                for (int r = 0; r < 4; r++) runmax[i][r] = -3.4e38f;
            }
        };
        auto consume = [&](int tk) {
            int buf1 = tk & 1;
            int n0 = base + tk * NB2;
            #pragma unroll
            for (int nl = 0; nl < NB2; nl++) {
                int g = (n0 + nl) / NPG;
                if (g != gprev) { flushfn(); gprev = g; }
                bf16x8 hA[8];
                #pragma unroll
                for (int kt = 0; kt < 8; kt++)
                    hA[kt] = *(const bf16x8*)&hidF[buf1][((nl * 8 + kt) * 64 + lane) * 8];
                f32x4 acc[2];
                f32x4 z = {0.f, 0.f, 0.f, 0.f};
                acc[0] = z; acc[1] = z;
                #pragma unroll
                for (int kt = 0; kt < 8; kt++) {
                    #pragma unroll
                    for (int i = 0; i < 2; i++) acc[i] = MFMA16(hA[kt], B2r[i][kt], acc[i]);
                }
                #pragma unroll
                for (int i = 0; i < 2; i++)
                    #pragma unroll
                    for (int r = 0; r < 4; r++)
                        runmax[i][r] = fmaxf(runmax[i][r], acc[i][r]);
            }
        };

        for (int k = 0; k < NT2; k++) {
            ldsbar();
            consume(k);
        }
        flushfn();
    }
}

// =================== head: fused, 16 blocks x 1024, 4-way k-split ===========
__global__ __launch_bounds__(1024) void head_kernel(
    const unsigned int* __restrict__ pooled,
    const float* __restrict__ fc1_W, const float* __restrict__ fc1_b,
    const float* __restrict__ fc2_W, const float* __restrict__ fc2_b,
    const float* __restrict__ lab_W, const float* __restrict__ lab_b,
    const float* __restrict__ box_W, const float* __restrict__ box_b,
    float* __restrict__ out)
{
    __shared__ float p[256], h1s[256], h2s[128], red[1024];
    const int g = blockIdx.x, tid = threadIdx.x;
    if (tid < 256) {
        unsigned u = pooled[g * 256 + tid];
        u = (u & 0x80000000u) ? (u & 0x7fffffffu) : ~u;
        p[tid] = __uint_as_float(u);
    }
    __syncthreads();
    {
        int c = tid & 255, kq = tid >> 8;
        float a = 0.f;
        #pragma unroll 8
        for (int k0 = 0; k0 < 64; k0++) {
            int k = kq * 64 + k0;
            a += p[k] * fc1_W[k * 256 + c];
        }
        red[tid] = a;
    }
    __syncthreads();
    if (tid < 256)
        h1s[tid] = fmaxf(red[tid] + red[256 + tid] + red[512 + tid] + red[768 + tid]
                         + fc1_b[tid], 0.f);
    __syncthreads();
    if (tid < 512) {
        int c = tid & 127, kq = tid >> 7;
        float a = 0.f;
        #pragma unroll 8
        for (int k0 = 0; k0 < 64; k0++) {
            int k = kq * 64 + k0;
            a += h1s[k] * fc2_W[k * 128 + c];
        }
        red[tid] = a;
    }
    __syncthreads();
    if (tid < 128)
        h2s[tid] = fmaxf(red[tid] + red[128 + tid] + red[256 + tid] + red[384 + tid]
                         + fc2_b[tid], 0.f);
    __syncthreads();
    if (tid < 128) {
        int o = tid >> 3, kq = tid & 7;
        float a = 0.f;
        #pragma unroll
        for (int k0 = 0; k0 < 16; k0++) {
            int k = kq * 16 + k0;
            float w = (o < 10) ? lab_W[k * 10 + o] : box_W[k * 6 + (o - 10)];
            a += h2s[k] * w;
        }
        red[tid] = a;
    }
    __syncthreads();
    if (tid < 16) {
        float a = 0.f;
        #pragma unroll
        for (int q = 0; q < 8; q++) a += red[tid * 8 + q];
        if (tid < 10) out[g * 10 + tid] = a + lab_b[tid];
        else          out[160 + g * 6 + (tid - 10)] = a + box_b[tid - 10];
    }
}

extern "C" void kernel_launch(void* const* d_in, const int* in_sizes, int n_in,
                              void* d_out, int out_size, void* d_ws, size_t ws_size,
                              hipStream_t stream) {
    const float* pos   = (const float*)d_in[0];
    const int*   esrc  = (const int*)  d_in[1];
    const float* c1W1 = (const float*)d_in[4];
    const float* c1b1 = (const float*)d_in[5];
    const float* c1W2 = (const float*)d_in[6];
    const float* c1b2 = (const float*)d_in[7];
    const float* c2W1 = (const float*)d_in[8];
    const float* c2b1 = (const float*)d_in[9];
    const float* c2W2 = (const float*)d_in[10];
    const float* c2b2 = (const float*)d_in[11];
    const float* fc1W = (const float*)d_in[12];
    const float* fc1b = (const float*)d_in[13];
    const float* fc2W = (const float*)d_in[14];
    const float* fc2b = (const float*)d_in[15];
    const float* labW = (const float*)d_in[16];
    const float* labb = (const float*)d_in[17];
    const float* boxW = (const float*)d_in[18];
    const float* boxb = (const float*)d_in[19];

    __bf16* wsb = (__bf16*)d_ws;
    __bf16* x1   = wsb + OFF_X1;
    __bf16* p1   = wsb + OFF_P1;
    __bf16* p2   = wsb + OFF_P2;
    __bf16* p3   = wsb + OFF_P3;
    __bf16* p4   = wsb + OFF_P4;
    __bf16* msgE = wsb + OFF_MSGE;
    unsigned int* pooled = (unsigned int*)((char*)d_ws + OFF_POOL_BYTES);

    prep_kernel<<<1250, 256, 0, stream>>>(pos, esrc, c1W1, c1W2, c2W1, c2W2,
                                          p1, p2, p3, p4, pooled, msgE);
    conv1_kernel<<<N_NODES / (NB1T * NT1), 512, 0, stream>>>(msgE, p1, c1b1, p2, c1b2, x1);
    conv2_kernel<<<N_NODES / (NB2 * NT2), 768, 0, stream>>>(esrc, x1, msgE, p3, c2b1, p4, c2b2, pooled);
    head_kernel<<<GRAPHS, 1024, 0, stream>>>(pooled, fc1W, fc1b, fc2W, fc2b,
                                             labW, labb, boxW, boxb, (float*)d_out);
}

// Round 17
// 181.757 us; speedup vs baseline: 1.0198x; 1.0198x over previous
//
#include <hip/hip_runtime.h>

#define N_NODES 20000
#define DEG 16
#define GRAPHS 16
#define NPG 1250

typedef __bf16 bf16x8 __attribute__((ext_vector_type(8)));
typedef float f32x4 __attribute__((ext_vector_type(4)));
#define MFMA16(a, b, c) __builtin_amdgcn_mfma_f32_16x16x32_bf16(a, b, c, 0, 0, 0)

// LDS-only barrier: waits LDS ops, does NOT drain vmcnt.
__device__ __forceinline__ void ldsbar() {
    __asm__ volatile("s_waitcnt lgkmcnt(0)\n\ts_barrier" ::: "memory");
}
// async global->LDS direct copy, 16 B per lane; LDS dest = uniform base + lane*16
__device__ __forceinline__ void async16(void* lds, const void* g) {
    __builtin_amdgcn_global_load_lds(
        (const __attribute__((address_space(1))) unsigned int*)(g),
        (__attribute__((address_space(3))) unsigned int*)(lds), 16, 0, 0);
}

// ---- workspace layout ----
#define OFF_X1    0            // x1 [20000][128] bf16
#define OFF_P1    2560000      // c1W1 packed: MT=8  KT=1 -> 4096
#define OFF_P2    2564096      // c1W2 packed: MT=8  KT=4 -> 16384
#define OFF_P3    2580480      // c2W1 packed: MT=16 KT=5 -> 40960
#define OFF_P4    2621440      // c2W2 packed: MT=16 KT=8 -> 65536
#define OFF_POOL_BYTES 5373952 // pooled u32[16*256]
#define OFF_MSGE  2695176      // msgE (bf16 elems): row e = [sx,sy,sz,rx,ry,rz,0,0]
#define ZROW      320000       //   row 320000 = zeros

// =================== prep: pack weights + pooled init + edge messages =========
__global__ __launch_bounds__(256) void prep_kernel(
    const float* __restrict__ pos, const int* __restrict__ esrc,
    const float* __restrict__ c1W1, const float* __restrict__ c1W2,
    const float* __restrict__ c2W1, const float* __restrict__ c2W2,
    __bf16* __restrict__ p1, __bf16* __restrict__ p2,
    __bf16* __restrict__ p3, __bf16* __restrict__ p4,
    unsigned int* __restrict__ pooled, __bf16* __restrict__ msgE)
{
    int t = blockIdx.x * 256 + threadIdx.x;
    {   // gatherE: one edge per thread
        int e = t, d = e >> 4;
        int s = esrc[e];
        float sx = pos[3*s], sy = pos[3*s+1], sz = pos[3*s+2];
        float dx = pos[3*d], dy = pos[3*d+1], dz = pos[3*d+2];
        bf16x8 v;
        v[0] = (__bf16)sx; v[1] = (__bf16)sy; v[2] = (__bf16)sz;
        v[3] = (__bf16)(sx - dx); v[4] = (__bf16)(sy - dy); v[5] = (__bf16)(sz - dz);
        v[6] = (__bf16)0.f; v[7] = (__bf16)0.f;
        *(bf16x8*)&msgE[(size_t)e * 8] = v;
    }
    if (t < GRAPHS * 256) pooled[t] = 0u;             // flipped(-inf) == 0
    if (t == 0) {
        bf16x8 z;
        #pragma unroll
        for (int j = 0; j < 8; j++) z[j] = (__bf16)0.f;
        *(bf16x8*)&msgE[(size_t)ZROW * 8] = z;
    }
    if (t >= 15872) return;
    const float* W; __bf16* out; int M, Kreal, KT, grp; bool c2w1 = false;
    if      (t <  512)  { W = c1W1; out = p1; M = 128; Kreal =   6; KT = 1; grp = t; }
    else if (t < 2560)  { W = c1W2; out = p2; M = 128; Kreal = 128; KT = 4; grp = t - 512; }
    else if (t < 7680)  { W = c2W1; out = p3; M = 256; Kreal = 131; KT = 5; grp = t - 2560; c2w1 = true; }
    else                { W = c2W2; out = p4; M = 256; Kreal = 256; KT = 8; grp = t - 7680; }
    int lane = grp & 63, rest = grp >> 6;
    int kt = rest % KT, mt = rest / KT;
    int m = mt * 16 + (lane & 15);
    int kbase = kt * 32 + ((lane >> 4) << 3);
    bf16x8 v;
    #pragma unroll
    for (int j = 0; j < 8; j++) {
        int ks = kbase + j;
        int wr;
        if (c2w1) wr = (ks < 128) ? ks : ((ks >= 131 && ks < 134) ? ks - 3 : -1);
        else      wr = (ks < Kreal) ? ks : -1;
        v[j] = (wr >= 0) ? (__bf16)W[wr * M + m] : (__bf16)0.f;
    }
    *(bf16x8*)&out[grp * 8] = v;
}

// =================== conv1 v4: 4 waves, 2 ch-tiles/wave, 2 blocks/CU =========
// 500 blocks x 256 thr x 40 nodes (NT1=5 tiles of NB1T=8). Each wave owns 2 of
// 8 channel-tiles in BOTH layers (A1[2]=16 + B2w[2][4]=64 regs — proven R9
// mapping). Halves hidF read amplification vs v3 (4 readers not 8); 56 KB LDS
// -> 2 blocks/CU for cross-block latency hiding. msgF triple-buffered DMA
// (2 async16/wave/tile, vmcnt(4)); lgkm-only barriers.
#define NB1T 8
#define NT1 5
__global__ __launch_bounds__(256, 2) void conv1_kernel(
    const __bf16* __restrict__ msgE,
    const __bf16* __restrict__ W1p, const float* __restrict__ b1,
    const __bf16* __restrict__ W2p, const float* __restrict__ b2,
    __bf16* __restrict__ x1)
{
    __shared__ __attribute__((aligned(16))) __bf16 msgF[3][NB1T * 64 * 8];   // 3x8 KB
    __shared__ __attribute__((aligned(16))) __bf16 hidF[NB1T * 4 * 64 * 8];  // 32 KB
    const int tid = threadIdx.x, lane = tid & 63, wave = tid >> 6;
    const int quad = lane >> 4, col = lane & 15;
    const int base = blockIdx.x * (NB1T * NT1);

    // resident: layer1 A-frags (2 mtiles), layer2 B-frags (2 ch-tiles)
    bf16x8 A1[2], B2w[2][4];
    f32x4 bias1[2];
    float b2v[2];
    #pragma unroll
    for (int i = 0; i < 2; i++) {
        int mtg = wave * 2 + i;
        A1[i] = *(const bf16x8*)&W1p[(mtg * 64 + lane) * 8];
        bias1[i] = *(const f32x4*)&b1[mtg * 16 + quad * 4];
        #pragma unroll
        for (int kt = 0; kt < 4; kt++)
            B2w[i][kt] = *(const bf16x8*)&W2p[((mtg * 4 + kt) * 64 + lane) * 8];
        b2v[i] = b2[mtg * 16 + col];
    }

    auto stage = [&](int td, int buf) {     // wave stages nodes {2w, 2w+1}
        #pragma unroll
        for (int s = 0; s < 2; s++) {
            int nl = wave * 2 + s;
            int row = (quad == 0) ? ((base + td * NB1T + nl) * 16 + col) : ZROW;
            async16(&msgF[buf][nl * 64 * 8], &msgE[(size_t)row * 8]);
        }
    };
    stage(0, 0);
    stage(1, 1);

    for (int k = 0; k < NT1; k++) {
        int td = k + 2; if (td >= NT1) td -= NT1;   // dummy tail keeps count uniform
        stage(td, (k + 2) % 3);
        __asm__ volatile("s_waitcnt vmcnt(4)" ::: "memory");  // tile-k DMAs done
        const int bufi = k % 3;
        // phase 1: D[ch][edge] for my 2 mtiles, all 8 nodes -> hidF
        #pragma unroll
        for (int nl = 0; nl < NB1T; nl++) {
            bf16x8 B = *(const bf16x8*)&msgF[bufi][(nl * 64 + lane) * 8];
            #pragma unroll
            for (int i = 0; i < 2; i++) {
                int mtg = wave * 2 + i;
                f32x4 acc = bias1[i];
                acc = MFMA16(A1[i], B, acc);
                union { __bf16 h[4]; uint2 u; } pk;
                #pragma unroll
                for (int r = 0; r < 4; r++) pk.h[r] = (__bf16)fmaxf(acc[r], 0.f);
                int kt2 = mtg >> 1;
                int lane2 = ((mtg * 2 + (quad >> 1)) & 3) * 16 + col;
                int j0 = (quad & 1) * 4;
                *(uint2*)&hidF[((nl * 4 + kt2) * 64 + lane2) * 8 + j0] = pk.u;
            }
        }
        ldsbar();                                   // hidF ready
        // phase 2: D[edge][ch] for my 2 ch-tiles, edge-max, store x1
        const int n0 = base + k * NB1T;
        #pragma unroll
        for (int nl = 0; nl < NB1T; nl++) {
            bf16x8 hA[4];
            #pragma unroll
            for (int kt = 0; kt < 4; kt++)
                hA[kt] = *(const bf16x8*)&hidF[((nl * 4 + kt) * 64 + lane) * 8];
            f32x4 acc[2];
            f32x4 z = {0.f, 0.f, 0.f, 0.f};
            acc[0] = z; acc[1] = z;
            #pragma unroll
            for (int kt = 0; kt < 4; kt++) {
                #pragma unroll
                for (int i = 0; i < 2; i++) acc[i] = MFMA16(hA[kt], B2w[i][kt], acc[i]);
            }
            #pragma unroll
            for (int i = 0; i < 2; i++) {
                float m = fmaxf(fmaxf(acc[i][0], acc[i][1]), fmaxf(acc[i][2], acc[i][3]));
                m = fmaxf(m, __shfl_xor(m, 16));
                m = fmaxf(m, __shfl_xor(m, 32));
                if (lane < 16)
                    x1[(size_t)(n0 + nl) * 128 + (wave * 2 + i) * 16 + lane] =
                        (__bf16)(m + b2v[i]);
            }
        }
        ldsbar();                                   // hidF free for next tile
    }
}

// =================== conv2 =================== (R15 512-thread version)
#define NB2 4
#define NT2 20
__global__ __launch_bounds__(512) __attribute__((amdgpu_waves_per_eu(2, 2)))
void conv2_kernel(
    const int* __restrict__ esrc,
    const __bf16* __restrict__ x1, const __bf16* __restrict__ msgE,
    const __bf16* __restrict__ W1p, const float* __restrict__ b1,
    const __bf16* __restrict__ W2p, const float* __restrict__ b2,
    unsigned int* __restrict__ pooled)
{
    __shared__ __attribute__((aligned(16))) __bf16 msgF[3][NB2 * 5 * 64 * 8];  // 3x20 KB
    __shared__ __attribute__((aligned(16))) __bf16 hidF[2][NB2 * 8 * 64 * 8];  // 2x32 KB
    __shared__ int sSrc[NB2 * NT2 * 16];                                       // 5.1 KB
    const int tid = threadIdx.x, lane = tid & 63, wave = tid >> 6;
    const int quad = lane >> 4, col = lane & 15;
    const int base = blockIdx.x * (NB2 * NT2);

    for (int u = tid; u < NB2 * NT2 * 16; u += 512) sSrc[u] = esrc[base * 16 + u];
    __syncthreads();

    if (wave < 4) {
        bf16x8 A1[4][5];
        f32x4 bias1[4];
        #pragma unroll
        for (int i = 0; i < 4; i++) {
            int tg = wave * 4 + i;
            #pragma unroll
            for (int kt = 0; kt < 5; kt++)
                A1[i][kt] = *(const bf16x8*)&W1p[((tg * 5 + kt) * 64 + lane) * 8];
            bias1[i] = *(const f32x4*)&b1[tg * 16 + quad * 4];
        }

        auto stage = [&](int td, int buf) {        // 20 groups / 4 waves = 5 each
            #pragma unroll
            for (int s = 0; s < 5; s++) {
                int g = wave + 4 * s;
                int nl = g / 5, kt = g % 5;
                __bf16* ldst = &msgF[buf][g * 64 * 8];
                const __bf16* gsrc;
                if (kt < 4) {
                    int src = sSrc[(td * NB2 + nl) * 16 + col];
                    gsrc = &x1[(size_t)src * 128 + kt * 32 + quad * 8];
                } else {
                    int row = (quad == 0) ? ((base + td * NB2 + nl) * 16 + col) : ZROW;
                    gsrc = &msgE[(size_t)row * 8];
                }
                async16(ldst, gsrc);
            }
        };

        stage(0, 0);
        stage(1, 1);

        for (int k = 0; k < NT2; k++) {
            int td = k + 2;
            if (td >= NT2) td -= NT2;
            stage(td, (k + 2) % 3);
            __asm__ volatile("s_waitcnt vmcnt(10)" ::: "memory");  // tile-k done
            const int bufi = k % 3, bufo = k & 1;
            #pragma unroll
            for (int nl = 0; nl < NB2; nl++) {
                bf16x8 B[5];
                #pragma unroll
                for (int kt = 0; kt < 5; kt++)
                    B[kt] = *(const bf16x8*)&msgF[bufi][((nl * 5 + kt) * 64 + lane) * 8];
                #pragma unroll
                for (int i = 0; i < 4; i++) {
                    int mtg = wave * 4 + i;
                    f32x4 acc = bias1[i];
                    #pragma unroll
                    for (int kt = 0; kt < 5; kt++) acc = MFMA16(A1[i][kt], B[kt], acc);
                    union { __bf16 h[4]; uint2 u; } pk;
                    #pragma unroll
                    for (int r = 0; r < 4; r++) pk.h[r] = (__bf16)fmaxf(acc[r], 0.f);
                    int kt2 = mtg >> 1;
                    int lane2 = ((mtg * 2 + (quad >> 1)) & 3) * 16 + col;
                    int j0 = (quad & 1) * 4;
                    *(uint2*)&hidF[bufo][((nl * 8 + kt2) * 64 + lane2) * 8 + j0] = pk.u;
                }
            }
            ldsbar();
        }
    } else {
        const int wv = wave - 4;
        bf16x8 B2r[4][8];
        #pragma unroll
        for (int i = 0; i < 4; i++) {
            int tg = wv * 4 + i;
            #pragma unroll
            for (int kt = 0; kt < 8; kt++)
                B2r[i][kt] = *(const bf16x8*)&W2p[((tg * 8 + kt) * 64 + lane) * 8];
        }
        f32x4 runmax[4];
        #pragma unroll
        for (int i = 0; i < 4; i++)
            #pragma unroll
            for (int r = 0; r < 4; r++) runmax[i][r] = -3.4e38f;
        int gprev = base / NPG;

        auto flushfn = [&]() {
            #pragma unroll
            for (int i = 0; i < 4; i++) {
                float v = fmaxf(fmaxf(runmax[i][0], runmax[i][1]),
                                fmaxf(runmax[i][2], runmax[i][3]));
                v = fmaxf(v, __shfl_xor(v, 16));
                v = fmaxf(v, __shfl_xor(v, 32));
                if (lane < 16) {
                    int c = (wv * 4 + i) * 16 + lane;
                    float val = v + b2[c];
                    unsigned u = __float_as_uint(val);
                    u = (u & 0x80000000u) ? ~u : (u | 0x80000000u);
                    atomicMax(&pooled[gprev * 256 + c], u);
                }
                #pragma unroll
                for (int r = 0; r < 4; r++) runmax[i][r] = -3.4e38f;
            }
        };
        auto consume = [&](int tk) {
            int buf1 = tk & 1;
            int n0 = base + tk * NB2;
            #pragma unroll
            for (int nl = 0; nl < NB2; nl++) {
                int g = (n0 + nl) / NPG;
                if (g != gprev) { flushfn(); gprev = g; }
                bf16x8 hA[8];
                #pragma unroll
                for (int kt = 0; kt < 8; kt++)
                    hA[kt] = *(const bf16x8*)&hidF[buf1][((nl * 8 + kt) * 64 + lane) * 8];
                f32x4 acc[4];
                f32x4 z = {0.f, 0.f, 0.f, 0.f};
                #pragma unroll
                for (int i = 0; i < 4; i++) acc[i] = z;
                #pragma unroll
                for (int kt = 0; kt < 8; kt++) {
                    #pragma unroll
                    for (int i = 0; i < 4; i++) acc[i] = MFMA16(hA[kt], B2r[i][kt], acc[i]);
                }
                #pragma unroll
                for (int i = 0; i < 4; i++)
                    #pragma unroll
                    for (int r = 0; r < 4; r++)
                        runmax[i][r] = fmaxf(runmax[i][r], acc[i][r]);
            }
        };

        for (int k = 0; k < NT2; k++) {
            ldsbar();
            consume(k);
        }
        flushfn();
    }
}

// =================== head: fused, 16 blocks x 1024, 4-way k-split ===========
__global__ __launch_bounds__(1024) void head_kernel(
    const unsigned int* __restrict__ pooled,
    const float* __restrict__ fc1_W, const float* __restrict__ fc1_b,
    const float* __restrict__ fc2_W, const float* __restrict__ fc2_b,
    const float* __restrict__ lab_W, const float* __restrict__ lab_b,
    const float* __restrict__ box_W, const float* __restrict__ box_b,
    float* __restrict__ out)
{
    __shared__ float p[256], h1s[256], h2s[128], red[1024];
    const int g = blockIdx.x, tid = threadIdx.x;
    if (tid < 256) {
        unsigned u = pooled[g * 256 + tid];
        u = (u & 0x80000000u) ? (u & 0x7fffffffu) : ~u;
        p[tid] = __uint_as_float(u);
    }
    __syncthreads();
    {
        int c = tid & 255, kq = tid >> 8;
        float a = 0.f;
        #pragma unroll 8
        for (int k0 = 0; k0 < 64; k0++) {
            int k = kq * 64 + k0;
            a += p[k] * fc1_W[k * 256 + c];
        }
        red[tid] = a;
    }
    __syncthreads();
    if (tid < 256)
        h1s[tid] = fmaxf(red[tid] + red[256 + tid] + red[512 + tid] + red[768 + tid]
                         + fc1_b[tid], 0.f);
    __syncthreads();
    if (tid < 512) {
        int c = tid & 127, kq = tid >> 7;
        float a = 0.f;
        #pragma unroll 8
        for (int k0 = 0; k0 < 64; k0++) {
            int k = kq * 64 + k0;
            a += h1s[k] * fc2_W[k * 128 + c];
        }
        red[tid] = a;
    }
    __syncthreads();
    if (tid < 128)
        h2s[tid] = fmaxf(red[tid] + red[128 + tid] + red[256 + tid] + red[384 + tid]
                         + fc2_b[tid], 0.f);
    __syncthreads();
    if (tid < 128) {
        int o = tid >> 3, kq = tid & 7;
        float a = 0.f;
        #pragma unroll
        for (int k0 = 0; k0 < 16; k0++) {
            int k = kq * 16 + k0;
            float w = (o < 10) ? lab_W[k * 10 + o] : box_W[k * 6 + (o - 10)];
            a += h2s[k] * w;
        }
        red[tid] = a;
    }
    __syncthreads();
    if (tid < 16) {
        float a = 0.f;
        #pragma unroll
        for (int q = 0; q < 8; q++) a += red[tid * 8 + q];
        if (tid < 10) out[g * 10 + tid] = a + lab_b[tid];
        else          out[160 + g * 6 + (tid - 10)] = a + box_b[tid - 10];
    }
}

extern "C" void kernel_launch(void* const* d_in, const int* in_sizes, int n_in,
                              void* d_out, int out_size, void* d_ws, size_t ws_size,
                              hipStream_t stream) {
    const float* pos   = (const float*)d_in[0];
    const int*   esrc  = (const int*)  d_in[1];
    const float* c1W1 = (const float*)d_in[4];
    const float* c1b1 = (const float*)d_in[5];
    const float* c1W2 = (const float*)d_in[6];
    const float* c1b2 = (const float*)d_in[7];
    const float* c2W1 = (const float*)d_in[8];
    const float* c2b1 = (const float*)d_in[9];
    const float* c2W2 = (const float*)d_in[10];
    const float* c2b2 = (const float*)d_in[11];
    const float* fc1W = (const float*)d_in[12];
    const float* fc1b = (const float*)d_in[13];
    const float* fc2W = (const float*)d_in[14];
    const float* fc2b = (const float*)d_in[15];
    const float* labW = (const float*)d_in[16];
    const float* labb = (const float*)d_in[17];
    const float* boxW = (const float*)d_in[18];
    const float* boxb = (const float*)d_in[19];

    __bf16* wsb = (__bf16*)d_ws;
    __bf16* x1   = wsb + OFF_X1;
    __bf16* p1   = wsb + OFF_P1;
    __bf16* p2   = wsb + OFF_P2;
    __bf16* p3   = wsb + OFF_P3;
    __bf16* p4   = wsb + OFF_P4;
    __bf16* msgE = wsb + OFF_MSGE;
    unsigned int* pooled = (unsigned int*)((char*)d_ws + OFF_POOL_BYTES);

    prep_kernel<<<1250, 256, 0, stream>>>(pos, esrc, c1W1, c1W2, c2W1, c2W2,
                                          p1, p2, p3, p4, pooled, msgE);
    conv1_kernel<<<N_NODES / (NB1T * NT1), 256, 0, stream>>>(msgE, p1, c1b1, p2, c1b2, x1);
    conv2_kernel<<<N_NODES / (NB2 * NT2), 512, 0, stream>>>(esrc, x1, msgE, p3, c2b1, p4, c2b2, pooled);
    head_kernel<<<GRAPHS, 1024, 0, stream>>>(pooled, fc1W, fc1b, fc2W, fc2b,
                                             labW, labb, boxW, boxb, (float*)d_out);
}